// Round 1
// baseline (295.288 us; speedup 1.0000x reference)
//
#include <hip/hip_runtime.h>
#include <math.h>

#define BS 131072
#define L 128
#define NCH 10
#define EMB 256
#define ZD 128
#define KCB 64
#define NF 290
#define RPB 64    // rows per block
#define TPB 128   // 2 waves

typedef __attribute__((ext_vector_type(8))) short short8;   // 8 bf16 = 4 VGPRs
typedef __attribute__((ext_vector_type(4))) float float4v;  // MFMA C/D

// ---- workspace float-offsets
#define WS_BC    0                    // combined bias [128]
#define WS_CNORM 128                  // ||code||^2 [64]
#define WS_CBT   192                  // codebook^T [128][64]
#define WS_CNT   8384                 // int counts [64]
#define WS_ESUM  8448                 // float e_sum
#define WS_WHI   8452                 // W_hi frags: 40960 bf16 (20480 floats), 16B-aligned
#define WS_WLO   28932                // W_lo frags: 40960 bf16

static __device__ __forceinline__ short f2bf(float x) {  // RNE fp32->bf16
  unsigned u = __float_as_uint(x);
  return (short)((u + 0x7fffu + ((u >> 16) & 1u)) >> 16);
}
static __device__ __forceinline__ float bf2f(short s) {
  return __uint_as_float(((unsigned)(unsigned short)s) << 16);
}

// ---------------- prep: fused W in B-fragment hi/lo layout, bias, cnorm, cbT, zeros
// W blocks: one block per fragment tile T=(c*2+ks)*8+nt, 80 blocks total.
// LDS-staged: fc_w columns transposed [32][260] (zero-padded for kl>=58),
// mu_w rows [16][260]. Each thread computes 2 outputs (same z, kl and kl+16).
__global__ void k_prep(const float* __restrict__ fc_w, const float* __restrict__ fc_b,
                       const float* __restrict__ mu_w, const float* __restrict__ mu_b,
                       const float* __restrict__ codebook, float* __restrict__ ws) {
  const int b = blockIdx.x, t = threadIdx.x;
  if (b < 80) {
    __shared__ float fcT[32 * 260];   // [kk][e], pad stride 260 -> bank = (4kk+e)%32
    __shared__ float mus[16 * 260];   // [zz][e]
    const int c = b >> 4, ks = (b >> 3) & 1, nt = b & 7;
    const int f0 = c * 58 + ks * 32;

    // stage fc columns (transposed), zero for invalid kl (>=58)
    {
      const int kk = t & 31, esub = t >> 5;             // 32 cols x 8 e-rows per pass
      const bool valid = (ks * 32 + kk) < 58;
#pragma unroll
      for (int p = 0; p < 32; ++p) {
        int e = p * 8 + esub;
        fcT[kk * 260 + e] = valid ? fc_w[e * NF + f0 + kk] : 0.0f;
      }
    }
    // stage mu rows as float4 (rows are 1KB contiguous)
    {
#pragma unroll
      for (int p = 0; p < 4; ++p) {
        int idx = p * 256 + t;
        int zz = idx >> 6, e4 = idx & 63;
        *(float4*)&mus[zz * 260 + e4 * 4] =
            *(const float4*)&mu_w[(nt * 16 + zz) * EMB + e4 * 4];
      }
    }
    __syncthreads();

    // thread t -> outputs (lane=lane_lo, j) and (lane=lane_lo+32, j); same z.
    const int lane_lo = t >> 3, j = t & 7;
    const int z = lane_lo & 15;
    const int kka = ((lane_lo >> 4) & 1) * 8 + j;       // kl local 0..15
    const int kkb = kka + 16;                           // kl local 16..31
    float a0 = 0, a1 = 0, a2 = 0, a3 = 0, b0 = 0, b1 = 0, b2 = 0, b3 = 0;
#pragma unroll 8
    for (int e = 0; e < 256; e += 4) {
      float4 m  = *(const float4*)&mus[z * 260 + e];
      float4 fa = *(const float4*)&fcT[kka * 260 + e];
      float4 fb = *(const float4*)&fcT[kkb * 260 + e];
      a0 = fmaf(m.x, fa.x, a0); a1 = fmaf(m.y, fa.y, a1);
      a2 = fmaf(m.z, fa.z, a2); a3 = fmaf(m.w, fa.w, a3);
      b0 = fmaf(m.x, fb.x, b0); b1 = fmaf(m.y, fb.y, b1);
      b2 = fmaf(m.z, fb.z, b2); b3 = fmaf(m.w, fb.w, b3);
    }
    float va = (a0 + a1) + (a2 + a3);
    float vb = (b0 + b1) + (b2 + b3);
    short* hi = (short*)(ws + WS_WHI);
    short* lo = (short*)(ws + WS_WLO);
    const int base = b * 512;
    short ha = f2bf(va); short la = f2bf(va - bf2f(ha));
    short hb = f2bf(vb); short lb = f2bf(vb - bf2f(hb));
    hi[base + t] = ha;        lo[base + t] = la;
    hi[base + 256 + t] = hb;  lo[base + 256 + t] = lb;
  } else if (b == 80) {
    if (t < ZD) {
      float p0 = 0, p1 = 0, p2 = 0, p3 = 0;
      const float* mw = mu_w + (size_t)t * EMB;
      for (int e = 0; e < EMB; e += 4) {
        p0 = fmaf(mw[e + 0], fc_b[e + 0], p0);
        p1 = fmaf(mw[e + 1], fc_b[e + 1], p1);
        p2 = fmaf(mw[e + 2], fc_b[e + 2], p2);
        p3 = fmaf(mw[e + 3], fc_b[e + 3], p3);
      }
      ws[WS_BC + t] = mu_b[t] + ((p0 + p1) + (p2 + p3));
    }
  } else if (b == 81) {
    if (t < KCB) {
      double acc = 0.0;
      for (int k = 0; k < ZD; ++k) { double v = (double)codebook[t * ZD + k]; acc += v * v; }
      ws[WS_CNORM + t] = (float)acc;
    } else if (t < 128) {
      ((int*)ws)[WS_CNT + (t - 64)] = 0;
    } else if (t == 128) {
      ws[WS_ESUM] = 0.0f;
    }
  } else {  // b == 82: codebook transpose -> [k][code]
    for (int i = 0; i < 32; ++i) {
      int idx = i * 256 + t;
      int k = idx >> 6, cc = idx & 63;
      ws[WS_CBT + idx] = codebook[cc * ZD + k];
    }
  }
}

// ---------------- fused main: conv+pool -> split-bf16 MFMA GEMM -> VQ -> z + loss partials
__launch_bounds__(TPB, 2)
__global__ void k_main(const float* __restrict__ pr, const int* __restrict__ mask,
                       const float* __restrict__ conv_w, const float* __restrict__ conv_b,
                       const float* __restrict__ codebook,
                       float* __restrict__ ws, float* __restrict__ out) {
  __shared__ __align__(16) unsigned char lds_raw[33024];  // feat_hi|feat_lo, later mu_s
  __shared__ float aux_val[RPB * 8];
  __shared__ int   aux_idx[RPB * 8];
  __shared__ int   bi_s[RPB];
  __shared__ float validf[RPB];
  __shared__ int   hist[KCB];

  short* feat_hi = (short*)lds_raw;            // [64][72] bf16, pitch 72 (144B, 16B-mult)
  short* feat_lo = (short*)(lds_raw + 9216);   // [64][72]
  float* mu_s    = (float*)lds_raw;            // [64][129] fp32, aliases feats after GEMM

  const int tid = threadIdx.x;
  const int lane = tid & 63, wv = tid >> 6;
  const int q4 = lane >> 4, c16 = lane & 15;
  const long rowg0 = (long)blockIdx.x * RPB;

  if (tid < KCB) hist[tid] = 0;
  // zero the K-pad (kl 58..63) once; conv never writes there, W frags are 0 there too
  for (int i = tid; i < RPB * 6; i += TPB) {
    int r = i / 6, kk = 58 + (i % 6);
    feat_hi[r * 72 + kk] = 0;
    feat_lo[r * 72 + kk] = 0;
  }

  // accumulators [mtile][ntile_local], init with fused bias (broadcast per C-col)
  const float* bc = ws + WS_BC;
  float4v acc[4][4];
#pragma unroll
  for (int ntl = 0; ntl < 4; ++ntl) {
    float bv = bc[wv * 64 + ntl * 16 + c16];
    float4v b4 = {bv, bv, bv, bv};
#pragma unroll
    for (int mt = 0; mt < 4; ++mt) acc[mt][ntl] = b4;
  }

  const short* whi = (const short*)(ws + WS_WHI);
  const short* wlo = (const short*)(ws + WS_WLO);

  // conv mapping: row = tid>>1, j-half = tid&1
  const int cr = tid >> 1, hh = tid & 1;
  const float* prow = pr + (rowg0 + cr) * (long)L;
  const int j0 = hh * 15, njj = 15 - hh;

#pragma unroll 1
  for (int ck = 0; ck < 5; ++ck) {
    // ---- conv+pool for channels 2ck, 2ck+1 -> bf16 hi/lo into feat buffers
#pragma unroll 1
    for (int chl = 0; chl < 2; ++chl) {
      const int ch = ck * 2 + chl;
      float w[12];
#pragma unroll
      for (int u = 0; u < 12; ++u) w[u] = conv_w[ch * 12 + u];
      const float cbias = conv_b[ch];

      float wb[20];                              // circular window: 5 float4 slots
      *(float4*)&wb[0]  = *(const float4*)&prow[4 * j0];
      *(float4*)&wb[4]  = *(const float4*)&prow[4 * j0 + 4];
      *(float4*)&wb[8]  = *(const float4*)&prow[4 * j0 + 8];
      *(float4*)&wb[12] = *(const float4*)&prow[4 * j0 + 12];
#pragma unroll
      for (int jj = 0; jj < 15; ++jj) {
        if (jj < njj) {
          int j = j0 + jj;
          if (jj + 1 < njj)
            *(float4*)&wb[((jj + 4) % 5) * 4] = *(const float4*)&prow[4 * j + 16];
          float m4 = -1e30f;
#pragma unroll
          for (int d = 0; d < 4; ++d) {
            float a = cbias;
#pragma unroll
            for (int u = 0; u < 12; ++u) a = fmaf(w[u], wb[(4 * jj + d + u) % 20], a);
            m4 = fmaxf(m4, a);
          }
          float v = fmaxf(m4, 0.0f);             // relu(max) == max(relu)
          int kl = chl * 29 + j;
          short h = f2bf(v);
          feat_hi[cr * 72 + kl] = h;
          feat_lo[cr * 72 + kl] = f2bf(v - bf2f(h));
        }
      }
    }
    __syncthreads();

    // ---- GEMM chunk: K=64 (2 MFMA ksteps), split-bf16 (3 MFMAs per tile-kstep)
#pragma unroll
    for (int ks = 0; ks < 2; ++ks) {
      short8 ah[4], al[4];
#pragma unroll
      for (int mt = 0; mt < 4; ++mt) {
        int off = (mt * 16 + c16) * 72 + ks * 32 + q4 * 8;
        ah[mt] = *(const short8*)(feat_hi + off);
        al[mt] = *(const short8*)(feat_lo + off);
      }
#pragma unroll
      for (int ntl = 0; ntl < 4; ++ntl) {
        int nt = wv * 4 + ntl;
        int fo = (((ck * 2 + ks) * 8 + nt) * 64 + lane) * 8;
        short8 bh = *(const short8*)(whi + fo);
        short8 bl = *(const short8*)(wlo + fo);
#pragma unroll
        for (int mt = 0; mt < 4; ++mt) {
          acc[mt][ntl] = __builtin_amdgcn_mfma_f32_16x16x32_bf16(ah[mt], bh, acc[mt][ntl], 0, 0, 0);
          acc[mt][ntl] = __builtin_amdgcn_mfma_f32_16x16x32_bf16(ah[mt], bl, acc[mt][ntl], 0, 0, 0);
          acc[mt][ntl] = __builtin_amdgcn_mfma_f32_16x16x32_bf16(al[mt], bh, acc[mt][ntl], 0, 0, 0);
        }
      }
    }
    __syncthreads();   // protects feat rewrite next chunk AND mu_s alias after loop
  }

  // ---- C-layout store to mu_s: row = mt*16 + q4*4 + r, col = wv*64 + ntl*16 + c16
#pragma unroll
  for (int mt = 0; mt < 4; ++mt)
#pragma unroll
    for (int ntl = 0; ntl < 4; ++ntl) {
      int col = wv * 64 + ntl * 16 + c16;
      int rowb = mt * 16 + q4 * 4;
#pragma unroll
      for (int r = 0; r < 4; ++r)
        mu_s[(rowb + r) * 129 + col] = acc[mt][ntl][r];
    }
  __syncthreads();

  // ---- VQ distances: thread tile 4 rows x 8 codes (fp32 exact, as round 1)
  const float* cnorm = ws + WS_CNORM;
  const float* cbT   = ws + WS_CBT;
  const int tvr = tid & 15, tvc = tid >> 4;
  const int rv0 = tvr * 4, cbo = tvc * 8;
  float s[4][8];
#pragma unroll
  for (int i = 0; i < 4; ++i)
#pragma unroll
    for (int j = 0; j < 8; ++j) s[i][j] = 0.0f;
#pragma unroll 4
  for (int k = 0; k < 128; ++k) {
    float m0 = mu_s[(rv0 + 0) * 129 + k];
    float m1 = mu_s[(rv0 + 1) * 129 + k];
    float m2 = mu_s[(rv0 + 2) * 129 + k];
    float m3 = mu_s[(rv0 + 3) * 129 + k];
    float4 ca = *(const float4*)&cbT[k * 64 + cbo];
    float4 cb4 = *(const float4*)&cbT[k * 64 + cbo + 4];
    float cv[8] = {ca.x, ca.y, ca.z, ca.w, cb4.x, cb4.y, cb4.z, cb4.w};
    float mv[4] = {m0, m1, m2, m3};
#pragma unroll
    for (int i = 0; i < 4; ++i)
#pragma unroll
      for (int j = 0; j < 8; ++j) s[i][j] = fmaf(mv[i], cv[j], s[i][j]);
  }
  {
    float4 n0 = *(const float4*)&cnorm[cbo];
    float4 n1 = *(const float4*)&cnorm[cbo + 4];
    float nv[8] = {n0.x, n0.y, n0.z, n0.w, n1.x, n1.y, n1.z, n1.w};
#pragma unroll
    for (int i = 0; i < 4; ++i) {
      float best = nv[0] - 2.0f * s[i][0];
      int bi = cbo;
#pragma unroll
      for (int j = 1; j < 8; ++j) {
        float d = nv[j] - 2.0f * s[i][j];
        if (d < best) { best = d; bi = cbo + j; }
      }
      aux_val[(rv0 + i) * 8 + tvc] = best;
      aux_idx[(rv0 + i) * 8 + tvc] = bi;
    }
  }
  __syncthreads();

  if (tid < RPB) {
    float best = aux_val[tid * 8];
    int bi = aux_idx[tid * 8];
#pragma unroll
    for (int v = 1; v < 8; ++v) {
      float x = aux_val[tid * 8 + v];
      if (x < best) { best = x; bi = aux_idx[tid * 8 + v]; }
    }
    bi_s[tid] = bi;
    validf[tid] = (mask[rowg0 + tid] == 0) ? 1.0f : 0.0f;
  }
  __syncthreads();
  if (tid < RPB) {
    if (validf[tid] > 0.5f) atomicAdd(&hist[bi_s[tid]], 1);
  }
  __syncthreads();
  if (tid < KCB && hist[tid] > 0) atomicAdd(&((int*)ws)[WS_CNT + tid], hist[tid]);

  // ---- z gather-write (coalesced) + commitment partial
  float eloc = 0.0f;
  float* zout = out + rowg0 * ZD;
#pragma unroll 2
  for (int p = 0; p < RPB; ++p) {
    int bi = bi_s[p];
    float q = codebook[bi * ZD + tid];
    float m = mu_s[p * 129 + tid];
    zout[(size_t)p * ZD + tid] = q;
    float d = q - m;
    eloc += validf[p] * d * d;
  }
#pragma unroll
  for (int o = 32; o > 0; o >>= 1) eloc += __shfl_xor(eloc, o, 64);
  if ((tid & 63) == 0) atomicAdd(&ws[WS_ESUM], eloc);
}

// ---------------- finalize scalars
__global__ void k_final(const float* __restrict__ ws, float* __restrict__ out) {
  int t = threadIdx.x;   // 64 threads
  const int* cnt = (const int*)ws + WS_CNT;
  double c = (double)cnt[t];
  double nv = c;
#pragma unroll
  for (int o = 32; o > 0; o >>= 1) nv += __shfl_xor(nv, o, 64);
  nv = fmax(nv, 1.0);
  double p = c / nv;
  double h = p * log(p + 1e-10);
#pragma unroll
  for (int o = 32; o > 0; o >>= 1) h += __shfl_xor(h, o, 64);
  if (t == 0) {
    out[(size_t)BS * ZD]     = (float)(0.25 * (double)ws[WS_ESUM] / (nv * 128.0));
    out[(size_t)BS * ZD + 1] = (float)exp(-h);
  }
}

extern "C" void kernel_launch(void* const* d_in, const int* in_sizes, int n_in,
                              void* d_out, int out_size, void* d_ws, size_t ws_size,
                              hipStream_t stream) {
  const float* pr      = (const float*)d_in[0];
  const int*   mask    = (const int*)d_in[1];
  const float* conv_w  = (const float*)d_in[2];
  const float* conv_b  = (const float*)d_in[3];
  const float* fc_w    = (const float*)d_in[4];
  const float* fc_b    = (const float*)d_in[5];
  const float* mu_w    = (const float*)d_in[6];
  const float* mu_b    = (const float*)d_in[7];
  const float* codebook= (const float*)d_in[8];
  float* ws  = (float*)d_ws;
  float* out = (float*)d_out;

  hipLaunchKernelGGL(k_prep, dim3(83), dim3(256), 0, stream,
                     fc_w, fc_b, mu_w, mu_b, codebook, ws);
  hipLaunchKernelGGL(k_main, dim3(BS / RPB), dim3(TPB), 0, stream,
                     pr, mask, conv_w, conv_b, codebook, ws, out);
  hipLaunchKernelGGL(k_final, dim3(1), dim3(64), 0, stream, ws, out);
}